// Round 1
// baseline (3406.723 us; speedup 1.0000x reference)
//
#include <hip/hip_runtime.h>
#include <hip/hip_fp16.h>
#include <stdint.h>

#define NROWS   262144
#define LSLOTS  32
#define S1      256
#define S2      128
#define S3      16
#define VOCAB   185
#define THRESHV 0.9921875f

#define CHUNK   16          // s-values per LDS chunk
#define RSTR    12          // LDS row stride in u32 (48 B: 16B-aligned, bank-friendly)
#define TPB     256

__device__ __forceinline__ __half2 u2h(uint32_t u) {
  union { uint32_t u; __half2 h; } x; x.u = u; return x.h;
}
__device__ __forceinline__ float clampv(float x) {
  return fminf(fmaxf(x, -THRESHV), THRESHV);
}

// stage CHUNK columns [c0, c0+16) of a [VOCAB, width] fp32 table into LDS as f16
__device__ __forceinline__ void stage_tbl(uint32_t* lds, const float* __restrict__ tbl,
                                          int width, int c0, int tid) {
  #pragma unroll 1
  for (int i = tid; i < VOCAB * (CHUNK / 2); i += TPB) {
    int v = i >> 3;
    int p = i & 7;
    int s = c0 + (p << 1);
    float x0 = tbl[v * width + s];
    float x1 = tbl[v * width + s + 1];
    union { __half2 h; uint32_t u; } cv;
    cv.h = __floats2half2_rn(x0, x1);   // low = even s
    lds[v * RSTR + p] = cv.u;
  }
}

__global__ __launch_bounds__(TPB, 3)
void rengar_fwd(const int* __restrict__ pst_idx,
                const float* __restrict__ color_sign,
                const float* __restrict__ sob_sign,
                const float* __restrict__ wtm,
                const float* __restrict__ emb_fs,
                const float* __restrict__ emb_va,
                const float* __restrict__ emb_ha,
                const float* __restrict__ emb_ra,
                const float* __restrict__ tempo_w,
                const float* __restrict__ fs_w,
                const float* __restrict__ fs_b,
                const float* __restrict__ absva_w,
                const float* __restrict__ absha_w,
                const float* __restrict__ absra_w,
                const float* __restrict__ va_w,
                const float* __restrict__ fsxva_w,
                const float* __restrict__ haxra_w,
                const float* __restrict__ out_va_w,
                const float* __restrict__ out_fsxva_w,
                float* __restrict__ out)
{
  __shared__ __align__(16) uint32_t lds_a[VOCAB * RSTR];
  __shared__ __align__(16) uint32_t lds_b[VOCAB * RSTR];

  const int tid = threadIdx.x;
  const int row = blockIdx.x * TPB + tid;

  // ---- per-row constants: indices packed 4x u8 per u32 ----
  uint32_t idxp[8];
  {
    const int4* ip = (const int4*)(pst_idx + (size_t)row * LSLOTS);
    #pragma unroll
    for (int k = 0; k < 8; ++k) {
      int4 t = ip[k];
      idxp[k] = (uint32_t)t.x | ((uint32_t)t.y << 8) |
                ((uint32_t)t.z << 16) | ((uint32_t)t.w << 24);
    }
  }
  const float wt = wtm[row];

  float fs2a[S3], va2a[S3];
  #pragma unroll
  for (int j = 0; j < S3; ++j) { fs2a[j] = 0.f; va2a[j] = 0.f; }

  // ================= phase 1 : fs / va (width S1) =================
  {
    __half2 cw[16];   // color pairs (l even in low)
    {
      const float4* cp = (const float4*)(color_sign + (size_t)row * LSLOTS);
      #pragma unroll
      for (int k = 0; k < 8; ++k) {
        float4 c4 = cp[k];
        cw[2 * k]     = __floats2half2_rn(c4.x, c4.y);
        cw[2 * k + 1] = __floats2half2_rn(c4.z, c4.w);
      }
    }

    #pragma unroll 1
    for (int c0 = 0; c0 < S1; c0 += CHUNK) {
      __syncthreads();
      stage_tbl(lds_a, emb_fs, S1, c0, tid);
      stage_tbl(lds_b, emb_va, S1, c0, tid);
      __syncthreads();

      __half2 f1[8], v1[8];
      #pragma unroll
      for (int p = 0; p < 8; ++p) {
        f1[p] = __float2half2_rn(0.f);
        v1[p] = __float2half2_rn(0.f);
      }

      #pragma unroll
      for (int l = 0; l < LSLOTS; ++l) {
        int v = (idxp[l >> 2] >> ((l & 3) * 8)) & 255;
        const uint4* ra = (const uint4*)(lds_a + v * RSTR);
        const uint4* rb = (const uint4*)(lds_b + v * RSTR);
        uint4 A0 = ra[0], A1 = ra[1];
        uint4 B0 = rb[0], B1 = rb[1];
        __half  cl = (l & 1) ? __high2half(cw[l >> 1]) : __low2half(cw[l >> 1]);
        __half2 c2 = __half2half2(cl);
        f1[0] = __hadd2(f1[0], u2h(A0.x));
        f1[1] = __hadd2(f1[1], u2h(A0.y));
        f1[2] = __hadd2(f1[2], u2h(A0.z));
        f1[3] = __hadd2(f1[3], u2h(A0.w));
        f1[4] = __hadd2(f1[4], u2h(A1.x));
        f1[5] = __hadd2(f1[5], u2h(A1.y));
        f1[6] = __hadd2(f1[6], u2h(A1.z));
        f1[7] = __hadd2(f1[7], u2h(A1.w));
        v1[0] = __hfma2(c2, u2h(B0.x), v1[0]);
        v1[1] = __hfma2(c2, u2h(B0.y), v1[1]);
        v1[2] = __hfma2(c2, u2h(B0.z), v1[2]);
        v1[3] = __hfma2(c2, u2h(B0.w), v1[3]);
        v1[4] = __hfma2(c2, u2h(B1.x), v1[4]);
        v1[5] = __hfma2(c2, u2h(B1.y), v1[5]);
        v1[6] = __hfma2(c2, u2h(B1.z), v1[6]);
        v1[7] = __hfma2(c2, u2h(B1.w), v1[7]);
      }

      float fa[CHUNK], vb[CHUNK];
      #pragma unroll
      for (int p = 0; p < 8; ++p) {
        float2 xf = __half22float2(f1[p]);
        float2 xv = __half22float2(v1[p]);
        fa[2 * p] = xf.x; fa[2 * p + 1] = xf.y;
        vb[2 * p] = xv.x; vb[2 * p + 1] = xv.y;
      }

      #pragma unroll
      for (int s = 0; s < CHUNK; ++s) {
        int sg = c0 + s;
        float a  = clampv(fa[s]);
        float b  = clampv(vb[s] + wt * tempo_w[sg]);   // tempo before clamp
        float ab = a * b;
        float nb = fabsf(b);
        #pragma unroll
        for (int j = 0; j < S3; ++j) {
          fs2a[j] += a  * fs_w[j * S1 + sg]  + nb * absva_w[j * S1 + sg];
          va2a[j] += b  * va_w[j * S1 + sg]  + ab * fsxva_w[j * S1 + sg];
        }
      }
    }
  }

  // ================= phase 2 : ha / ra (width S2) =================
  {
    __half2 sw[32];   // per-l: (sob, color*sob)
    {
      const float4* cp = (const float4*)(color_sign + (size_t)row * LSLOTS);
      const float4* sp = (const float4*)(sob_sign  + (size_t)row * LSLOTS);
      #pragma unroll
      for (int k = 0; k < 8; ++k) {
        float4 c4 = cp[k];
        float4 s4 = sp[k];
        sw[4 * k + 0] = __floats2half2_rn(s4.x, c4.x * s4.x);
        sw[4 * k + 1] = __floats2half2_rn(s4.y, c4.y * s4.y);
        sw[4 * k + 2] = __floats2half2_rn(s4.z, c4.z * s4.z);
        sw[4 * k + 3] = __floats2half2_rn(s4.w, c4.w * s4.w);
      }
    }

    #pragma unroll 1
    for (int c0 = 0; c0 < S2; c0 += CHUNK) {
      __syncthreads();
      stage_tbl(lds_a, emb_ha, S2, c0, tid);
      stage_tbl(lds_b, emb_ra, S2, c0, tid);
      __syncthreads();

      __half2 h1[8], r1[8];
      #pragma unroll
      for (int p = 0; p < 8; ++p) {
        h1[p] = __float2half2_rn(0.f);
        r1[p] = __float2half2_rn(0.f);
      }

      #pragma unroll
      for (int l = 0; l < LSLOTS; ++l) {
        int v = (idxp[l >> 2] >> ((l & 3) * 8)) & 255;
        const uint4* ra = (const uint4*)(lds_a + v * RSTR);
        const uint4* rb = (const uint4*)(lds_b + v * RSTR);
        uint4 A0 = ra[0], A1 = ra[1];
        uint4 B0 = rb[0], B1 = rb[1];
        __half2 wh = __half2half2(__low2half(sw[l]));
        __half2 wr = __half2half2(__high2half(sw[l]));
        h1[0] = __hfma2(wh, u2h(A0.x), h1[0]);
        h1[1] = __hfma2(wh, u2h(A0.y), h1[1]);
        h1[2] = __hfma2(wh, u2h(A0.z), h1[2]);
        h1[3] = __hfma2(wh, u2h(A0.w), h1[3]);
        h1[4] = __hfma2(wh, u2h(A1.x), h1[4]);
        h1[5] = __hfma2(wh, u2h(A1.y), h1[5]);
        h1[6] = __hfma2(wh, u2h(A1.z), h1[6]);
        h1[7] = __hfma2(wh, u2h(A1.w), h1[7]);
        r1[0] = __hfma2(wr, u2h(B0.x), r1[0]);
        r1[1] = __hfma2(wr, u2h(B0.y), r1[1]);
        r1[2] = __hfma2(wr, u2h(B0.z), r1[2]);
        r1[3] = __hfma2(wr, u2h(B0.w), r1[3]);
        r1[4] = __hfma2(wr, u2h(B1.x), r1[4]);
        r1[5] = __hfma2(wr, u2h(B1.y), r1[5]);
        r1[6] = __hfma2(wr, u2h(B1.z), r1[6]);
        r1[7] = __hfma2(wr, u2h(B1.w), r1[7]);
      }

      float hf[CHUNK], rf[CHUNK];
      #pragma unroll
      for (int p = 0; p < 8; ++p) {
        float2 xh = __half22float2(h1[p]);
        float2 xr = __half22float2(r1[p]);
        hf[2 * p] = xh.x; hf[2 * p + 1] = xh.y;
        rf[2 * p] = xr.x; rf[2 * p + 1] = xr.y;
      }

      #pragma unroll
      for (int s = 0; s < CHUNK; ++s) {
        int sg = c0 + s;
        float h  = clampv(hf[s]);
        float r  = clampv(rf[s]);
        float ah = fabsf(h), ar = fabsf(r), hr = h * r;
        #pragma unroll
        for (int j = 0; j < S3; ++j) {
          fs2a[j] += ah * absha_w[j * S2 + sg] + ar * absra_w[j * S2 + sg];
          va2a[j] += hr * haxra_w[j * S2 + sg];
        }
      }
    }
  }

  // ================= epilogue =================
  float o = 0.f;
  #pragma unroll
  for (int j = 0; j < S3; ++j) {
    float f = clampv(fs2a[j] + fs_b[j]);   // bias before clamp
    float v = clampv(va2a[j]);
    o += v * out_va_w[j] + f * v * out_fsxva_w[j];
  }
  out[row] = o;
}

extern "C" void kernel_launch(void* const* d_in, const int* in_sizes, int n_in,
                              void* d_out, int out_size, void* d_ws, size_t ws_size,
                              hipStream_t stream) {
  const int*   pst_idx    = (const int*)  d_in[0];
  const float* color_sign = (const float*)d_in[1];
  const float* sob_sign   = (const float*)d_in[2];
  const float* wtm        = (const float*)d_in[3];
  const float* emb_fs     = (const float*)d_in[4];
  const float* emb_va     = (const float*)d_in[5];
  const float* emb_ha     = (const float*)d_in[6];
  const float* emb_ra     = (const float*)d_in[7];
  const float* tempo_w    = (const float*)d_in[8];
  const float* fs_w       = (const float*)d_in[9];
  const float* fs_b       = (const float*)d_in[10];
  const float* absva_w    = (const float*)d_in[11];
  const float* absha_w    = (const float*)d_in[12];
  const float* absra_w    = (const float*)d_in[13];
  const float* va_w       = (const float*)d_in[14];
  const float* fsxva_w    = (const float*)d_in[15];
  const float* haxra_w    = (const float*)d_in[16];
  const float* out_va_w   = (const float*)d_in[17];
  const float* out_fsxva_w= (const float*)d_in[18];
  float* out = (float*)d_out;

  rengar_fwd<<<NROWS / TPB, TPB, 0, stream>>>(
      pst_idx, color_sign, sob_sign, wtm, emb_fs, emb_va, emb_ha, emb_ra,
      tempo_w, fs_w, fs_b, absva_w, absha_w, absra_w, va_w, fsxva_w, haxra_w,
      out_va_w, out_fsxva_w, out);
}

// Round 2
// 808.811 us; speedup vs baseline: 4.2120x; 4.2120x over previous
//
#include <hip/hip_runtime.h>
#include <hip/hip_fp16.h>
#include <stdint.h>

typedef _Float16 f16;
typedef _Float16 f16x8 __attribute__((ext_vector_type(8)));
typedef float f32x4 __attribute__((ext_vector_type(4)));

#define NROWS 262144
#define MROWS 16            // rows per block
#define TPB   256
#define NBLK  (NROWS / MROWS)
#define K     192           // padded vocab
#define THR   0.9921875f

// workspace byte offsets (all f16)
#define WS_TABT 0                       // [768][192]
#define WS_W2FS (768 * 192 * 2)         // [16][768]
#define WS_W2VA (WS_W2FS + 16 * 768 * 2) // [16][640]

// LDS byte offsets (48 KiB total, time-multiplexed)
//  phase A: cntfx  int  [4][16][192]   @0      (49152)
//  phase B: cnt16  f16  [4][16][200]   @0      (25600)  in-place convert
//  phase C: fsfeat f16  [16][776]      @0      (24832)
//           vafeat f16  [16][648]      @24832  (20736)
//           exch   f32  [2][16][16]    @45568  (2048)
#define FS_STRIDE 776
#define VA_STRIDE 648
#define VA_BASE   24832
#define EX_BASE   45568

__device__ __forceinline__ f16x8 bc8(uint4 u) {
  union { uint4 u; f16x8 h; } x; x.u = u; return x.h;
}
__device__ __forceinline__ float clampv(float x) {
  return fminf(fmaxf(x, -THR), THR);
}

// ---------------- prepack: tables -> f16 transposed, weights -> f16 packed ----
__global__ void prepack(const float* __restrict__ emb_fs, const float* __restrict__ emb_va,
                        const float* __restrict__ emb_ha, const float* __restrict__ emb_ra,
                        const float* __restrict__ fs_w,   const float* __restrict__ absva_w,
                        const float* __restrict__ absha_w,const float* __restrict__ absra_w,
                        const float* __restrict__ va_w,   const float* __restrict__ fsxva_w,
                        const float* __restrict__ haxra_w, f16* __restrict__ ws) {
  int gid = blockIdx.x * 256 + threadIdx.x;
  if (gid < 768 * 192) {                       // tabT[u][k]
    int u = gid / 192, k = gid % 192;
    float v = 0.f;
    if (k < 185) {
      if      (u < 256) v = emb_fs[k * 256 + u];
      else if (u < 512) v = emb_va[k * 256 + (u - 256)];
      else if (u < 640) v = emb_ha[k * 128 + (u - 512)];
      else              v = emb_ra[k * 128 + (u - 640)];
    }
    ws[u * 192 + k] = (f16)v;
  } else if (gid < 768 * 192 + 16 * 768) {     // w2fs[j][k]
    int g = gid - 768 * 192;
    int j = g / 768, k = g % 768;
    float v = (k < 256) ? fs_w[j * 256 + k]
            : (k < 512) ? absva_w[j * 256 + (k - 256)]
            : (k < 640) ? absha_w[j * 128 + (k - 512)]
                        : absra_w[j * 128 + (k - 640)];
    ((f16*)((char*)ws + WS_W2FS))[j * 768 + k] = (f16)v;
  } else if (gid < 768 * 192 + 16 * 768 + 16 * 640) {  // w2va[j][k]
    int g = gid - 768 * 192 - 16 * 768;
    int j = g / 640, k = g % 640;
    float v = (k < 256) ? va_w[j * 256 + k]
            : (k < 512) ? fsxva_w[j * 256 + (k - 256)]
                        : haxra_w[j * 128 + (k - 512)];
    ((f16*)((char*)ws + WS_W2VA))[j * 640 + k] = (f16)v;
  }
}

// ---------------- main fused kernel ------------------------------------------
__global__ __launch_bounds__(TPB, 2)
void rengar_main(const int* __restrict__ pst_idx, const float* __restrict__ color_sign,
                 const float* __restrict__ sob_sign, const float* __restrict__ wtm,
                 const float* __restrict__ tempo_w, const float* __restrict__ fs_b,
                 const float* __restrict__ out_va_w, const float* __restrict__ out_fsxva_w,
                 const f16* __restrict__ ws, float* __restrict__ out) {
  __shared__ __align__(16) char smem[49152];

  const int tid  = threadIdx.x;
  const int lane = tid & 63;
  const int w    = tid >> 6;
  const int l15  = lane & 15;
  const int q    = lane >> 4;
  const int r0   = blockIdx.x * MROWS;

  const f16* tabT = (const f16*)((const char*)ws + WS_TABT);

  // ---- P1: zero count grid (4 tables x 16 rows x 192 k, int32 fixed-point)
  {
    int4 z = make_int4(0, 0, 0, 0);
    int4* p = (int4*)smem;
    #pragma unroll
    for (int i = 0; i < 12; ++i) p[tid + 256 * i] = z;
  }
  __syncthreads();

  // ---- P2: scatter (duplicate-safe via LDS int atomics, scale 2^16)
  {
    int* cntfx = (int*)smem;
    #pragma unroll
    for (int pp = 0; pp < 2; ++pp) {
      int p = tid + 256 * pp;                 // 0..511 = 16 rows x 32 slots
      int row = p >> 5;
      int g = r0 * 32 + p;                    // coalesced
      int v = pst_idx[g];
      float c = color_sign[g], s = sob_sign[g];
      int* base = cntfx + row * K + v;
      atomicAdd(base + 0 * MROWS * K, 65536);
      atomicAdd(base + 1 * MROWS * K, __float2int_rn(c * 65536.f));
      atomicAdd(base + 2 * MROWS * K, __float2int_rn(s * 65536.f));
      atomicAdd(base + 3 * MROWS * K, __float2int_rn(c * s * 65536.f));
    }
  }
  __syncthreads();

  // ---- P3: convert int -> f16 counts, in-place re-layout [tb][row][200]
  {
    int vals[48];
    const int4* src = (const int4*)smem;
    #pragma unroll
    for (int i = 0; i < 12; ++i) {
      int4 t4 = src[tid * 12 + i];
      vals[4 * i + 0] = t4.x; vals[4 * i + 1] = t4.y;
      vals[4 * i + 2] = t4.z; vals[4 * i + 3] = t4.w;
    }
    __syncthreads();                           // all reads done before any write
    int lin = 48 * tid;                        // 48 ints = 1/4 of one row
    int tb  = lin / 3072;
    int row = (lin / 192) & 15;
    int k0  = lin % 192;
    uint32_t* dst = (uint32_t*)smem + tb * 1600 + row * 100 + (k0 >> 1);
    const float inv = 1.f / 65536.f;
    #pragma unroll
    for (int i = 0; i < 24; ++i) {
      __half2 h = __floats2half2_rn(vals[2 * i] * inv, vals[2 * i + 1] * inv);
      union { __half2 h; uint32_t u; } cv; cv.h = h;
      dst[i] = cv.u;
    }
  }
  __syncthreads();

  // ---- P4: layer-1 GEMM. out^T tiles: A = tabT (global/L2), B = counts (LDS)
  f32x4 acc[12];
  {
    uint4 bfr[6];
    int tb_cur = -1;
    #pragma unroll
    for (int i = 0; i < 12; ++i) {
      int t  = w * 12 + i;
      int u0 = t * 16;
      int tb = (u0 < 256) ? 0 : (u0 < 512) ? 1 : (u0 < 640) ? 2 : 3;
      if (tb != tb_cur) {
        tb_cur = tb;
        #pragma unroll
        for (int ks = 0; ks < 6; ++ks) {
          const uint32_t* p = (const uint32_t*)smem + tb * 1600 + l15 * 100 + ks * 16 + q * 4;
          bfr[ks] = *(const uint4*)p;
        }
      }
      const f16* ap = tabT + (u0 + l15) * K + q * 8;
      uint4 afr[6];
      #pragma unroll
      for (int ks = 0; ks < 6; ++ks) afr[ks] = *(const uint4*)(ap + ks * 32);
      f32x4 a = {0.f, 0.f, 0.f, 0.f};
      #pragma unroll
      for (int ks = 0; ks < 6; ++ks)
        a = __builtin_amdgcn_mfma_f32_16x16x32_f16(bc8(afr[ks]), bc8(bfr[ks]), a, 0, 0, 0);
      acc[i] = a;
    }
  }
  __syncthreads();    // counts dead; LDS becomes feature space

  // ---- P5: primary features from D-regs (D: col=l15=row, m=q*4+reg=u)
  {
    const float wt = wtm[r0 + l15];
    #pragma unroll
    for (int i = 0; i < 12; ++i) {
      int t  = w * 12 + i;
      int u0 = t * 16;
      int tb = (u0 < 256) ? 0 : (u0 < 512) ? 1 : (u0 < 640) ? 2 : 3;
      int m0 = u0 + q * 4;
      f32x4 a = acc[i];
      if (tb == 0) {
        __half2* d = (__half2*)(smem + l15 * (FS_STRIDE * 2) + m0 * 2);
        d[0] = __floats2half2_rn(clampv(a[0]), clampv(a[1]));
        d[1] = __floats2half2_rn(clampv(a[2]), clampv(a[3]));
      } else if (tb == 1) {
        int s0 = m0 - 256;
        float b0 = clampv(a[0] + wt * tempo_w[s0 + 0]);
        float b1 = clampv(a[1] + wt * tempo_w[s0 + 1]);
        float b2 = clampv(a[2] + wt * tempo_w[s0 + 2]);
        float b3 = clampv(a[3] + wt * tempo_w[s0 + 3]);
        __half2* dv = (__half2*)(smem + VA_BASE + l15 * (VA_STRIDE * 2) + s0 * 2);
        dv[0] = __floats2half2_rn(b0, b1);
        dv[1] = __floats2half2_rn(b2, b3);
        __half2* df = (__half2*)(smem + l15 * (FS_STRIDE * 2) + (256 + s0) * 2);
        df[0] = __floats2half2_rn(fabsf(b0), fabsf(b1));
        df[1] = __floats2half2_rn(fabsf(b2), fabsf(b3));
      } else if (tb == 2) {
        int s0 = m0 - 512;     // signed h (temp)
        __half2* d = (__half2*)(smem + l15 * (FS_STRIDE * 2) + (512 + s0) * 2);
        d[0] = __floats2half2_rn(clampv(a[0]), clampv(a[1]));
        d[1] = __floats2half2_rn(clampv(a[2]), clampv(a[3]));
      } else {
        int s0 = m0 - 640;     // signed r (temp)
        __half2* d = (__half2*)(smem + l15 * (FS_STRIDE * 2) + (640 + s0) * 2);
        d[0] = __floats2half2_rn(clampv(a[0]), clampv(a[1]));
        d[1] = __floats2half2_rn(clampv(a[2]), clampv(a[3]));
      }
    }
  }
  __syncthreads();

  // ---- P6: derived features: ab, |h|, |r|, h*r
  {
    uint32_t* fs32 = (uint32_t*)smem;                 // row stride 388 u32
    uint32_t* va32 = (uint32_t*)(smem + VA_BASE);     // row stride 324 u32
    #pragma unroll
    for (int it = 0; it < 12; ++it) {
      int p = tid + 256 * it;                         // 0..3071
      if (p < 2048) {                                 // ab: 16 rows x 128 pairs
        int row = p >> 7, kp = p & 127;
        union { uint32_t u; __half2 h; } a, b, r;
        a.u = fs32[row * 388 + kp];
        b.u = va32[row * 324 + kp];
        r.h = __hmul2(a.h, b.h);
        va32[row * 324 + 128 + kp] = r.u;
      } else {                                        // |h|,|r|,hr: 16 x 64 pairs
        int pc = p - 2048;
        int row = pc >> 6, kp = pc & 63;
        union { uint32_t u; __half2 h; } h2, r2, pr;
        h2.u = fs32[row * 388 + 256 + kp];
        r2.u = fs32[row * 388 + 320 + kp];
        pr.h = __hmul2(h2.h, r2.h);
        fs32[row * 388 + 256 + kp] = h2.u & 0x7FFF7FFFu;
        fs32[row * 388 + 320 + kp] = r2.u & 0x7FFF7FFFu;
        va32[row * 324 + 256 + kp] = pr.u;
      }
    }
  }
  __syncthreads();

  // ---- P7: layer-2 GEMM (wave 0: fs side K=768; wave 1: va side K=640)
  float* exch = (float*)(smem + EX_BASE);
  if (w == 0) {
    const f16* A = (const f16*)((const char*)ws + WS_W2FS) + l15 * 768 + q * 8;
    f32x4 a2 = {0.f, 0.f, 0.f, 0.f};
    #pragma unroll
    for (int ks = 0; ks < 24; ++ks) {
      uint4 af = *(const uint4*)(A + ks * 32);
      uint4 bf = *(const uint4*)(smem + l15 * (FS_STRIDE * 2) + (ks * 32 + q * 8) * 2);
      a2 = __builtin_amdgcn_mfma_f32_16x16x32_f16(bc8(af), bc8(bf), a2, 0, 0, 0);
    }
    #pragma unroll
    for (int r = 0; r < 4; ++r) {
      int j = q * 4 + r;
      exch[j * 16 + l15] = clampv(a2[r] + fs_b[j]);
    }
  } else if (w == 1) {
    const f16* A = (const f16*)((const char*)ws + WS_W2VA) + l15 * 640 + q * 8;
    f32x4 a2 = {0.f, 0.f, 0.f, 0.f};
    #pragma unroll
    for (int ks = 0; ks < 20; ++ks) {
      uint4 af = *(const uint4*)(A + ks * 32);
      uint4 bf = *(const uint4*)(smem + VA_BASE + l15 * (VA_STRIDE * 2) + (ks * 32 + q * 8) * 2);
      a2 = __builtin_amdgcn_mfma_f32_16x16x32_f16(bc8(af), bc8(bf), a2, 0, 0, 0);
    }
    #pragma unroll
    for (int r = 0; r < 4; ++r) {
      int j = q * 4 + r;
      exch[256 + j * 16 + l15] = clampv(a2[r]);
    }
  }
  __syncthreads();

  // ---- P8: output: o[row] = sum_j v*w1[j] + f*v*w2[j]
  if (w == 0) {
    float o = 0.f;
    #pragma unroll
    for (int r = 0; r < 4; ++r) {
      int j = q * 4 + r;
      float f = exch[j * 16 + l15];
      float v = exch[256 + j * 16 + l15];
      o += v * out_va_w[j] + f * v * out_fsxva_w[j];
    }
    o += __shfl_xor(o, 16, 64);
    o += __shfl_xor(o, 32, 64);
    if (q == 0) out[r0 + l15] = o;
  }
}

extern "C" void kernel_launch(void* const* d_in, const int* in_sizes, int n_in,
                              void* d_out, int out_size, void* d_ws, size_t ws_size,
                              hipStream_t stream) {
  const int*   pst_idx     = (const int*)  d_in[0];
  const float* color_sign  = (const float*)d_in[1];
  const float* sob_sign    = (const float*)d_in[2];
  const float* wtm         = (const float*)d_in[3];
  const float* emb_fs      = (const float*)d_in[4];
  const float* emb_va      = (const float*)d_in[5];
  const float* emb_ha      = (const float*)d_in[6];
  const float* emb_ra      = (const float*)d_in[7];
  const float* tempo_w     = (const float*)d_in[8];
  const float* fs_w        = (const float*)d_in[9];
  const float* fs_b        = (const float*)d_in[10];
  const float* absva_w     = (const float*)d_in[11];
  const float* absha_w     = (const float*)d_in[12];
  const float* absra_w     = (const float*)d_in[13];
  const float* va_w        = (const float*)d_in[14];
  const float* fsxva_w     = (const float*)d_in[15];
  const float* haxra_w     = (const float*)d_in[16];
  const float* out_va_w    = (const float*)d_in[17];
  const float* out_fsxva_w = (const float*)d_in[18];
  float* out = (float*)d_out;
  f16* ws = (f16*)d_ws;

  prepack<<<664, 256, 0, stream>>>(emb_fs, emb_va, emb_ha, emb_ra,
                                   fs_w, absva_w, absha_w, absra_w,
                                   va_w, fsxva_w, haxra_w, ws);
  rengar_main<<<NBLK, TPB, 0, stream>>>(pst_idx, color_sign, sob_sign, wtm,
                                        tempo_w, fs_b, out_va_w, out_fsxva_w,
                                        ws, out);
}

// Round 3
// 494.974 us; speedup vs baseline: 6.8826x; 1.6340x over previous
//
#include <hip/hip_runtime.h>
#include <hip/hip_fp16.h>
#include <stdint.h>

typedef _Float16 f16;
typedef _Float16 f16x8 __attribute__((ext_vector_type(8)));
typedef float f32x4 __attribute__((ext_vector_type(4)));

#define NROWS 262144
#define MROWS 16            // rows per group
#define TPB   512           // 8 waves
#define GPB   8             // row-groups per block (table reused across these)
#define NBLK  (NROWS / (MROWS * GPB))   // 2048
#define K     192           // padded vocab
#define THR   0.9921875f

// workspace byte offsets (all f16)
#define WS_TABT 0                        // [768][192]
#define WS_W2FS (768 * 192 * 2)          // [16][768]
#define WS_W2VA (WS_W2FS + 16 * 768 * 2) // [16][640]

// LDS layout (time-multiplexed):
//  phase A: cntfx  int  [4][16][192]         @0      (49152)
//  phase B: cnt16  f16  [4][16][200]         @0      (25600)
//  phase C: fsfeat f16  [16][776]            @0      (24832)
//           vafeat f16  [16][648]            @24832  (20736)
//           exch   f32  [8][16][16]          @45568  (8192)
//           prod   f32  [16][16]             @53760  (1024)
#define FS_STRIDE 776
#define VA_STRIDE 648
#define VA_BASE   24832
#define EX_BASE   45568
#define PROD_BASE 53760
#define SMEM_SZ   54784

__device__ __forceinline__ f16x8 bc8(uint4 u) {
  union { uint4 u; f16x8 h; } x; x.u = u; return x.h;
}
__device__ __forceinline__ float clampv(float x) {
  return fminf(fmaxf(x, -THR), THR);
}

// ---------------- prepack ----------------------------------------------------
// blocks 0..23: table transpose via LDS tile (coalesced both sides)
// blocks 24.. : layer-2 weight pack (already coalesced)
__global__ void prepack(const float* __restrict__ emb_fs, const float* __restrict__ emb_va,
                        const float* __restrict__ emb_ha, const float* __restrict__ emb_ra,
                        const float* __restrict__ fs_w,   const float* __restrict__ absva_w,
                        const float* __restrict__ absha_w,const float* __restrict__ absra_w,
                        const float* __restrict__ va_w,   const float* __restrict__ fsxva_w,
                        const float* __restrict__ haxra_w, f16* __restrict__ ws) {
  if (blockIdx.x < 24) {
    __shared__ float tile[192 * 33];
    int u0 = blockIdx.x * 32;
    int t = threadIdx.x;
    #pragma unroll 4
    for (int i = 0; i < 24; ++i) {
      int idx = t + 256 * i;            // 6144 = 192k x 32u
      int k = idx >> 5;
      int c = idx & 31;
      int u = u0 + c;
      float v = 0.f;
      if (k < 185) {
        if      (u < 256) v = emb_fs[k * 256 + u];
        else if (u < 512) v = emb_va[k * 256 + (u - 256)];
        else if (u < 640) v = emb_ha[k * 128 + (u - 512)];
        else              v = emb_ra[k * 128 + (u - 640)];
      }
      tile[k * 33 + c] = v;
    }
    __syncthreads();
    #pragma unroll 4
    for (int i = 0; i < 24; ++i) {
      int idx = t + 256 * i;
      int u = idx / 192;
      int k = idx % 192;
      ws[(u0 + u) * 192 + k] = (f16)tile[k * 33 + u];
    }
  } else {
    int gid = (blockIdx.x - 24) * 256 + threadIdx.x;
    if (gid < 16 * 768) {                        // w2fs[j][k]
      int j = gid / 768, k = gid % 768;
      float v = (k < 256) ? fs_w[j * 256 + k]
              : (k < 512) ? absva_w[j * 256 + (k - 256)]
              : (k < 640) ? absha_w[j * 128 + (k - 512)]
                          : absra_w[j * 128 + (k - 640)];
      ((f16*)((char*)ws + WS_W2FS))[j * 768 + k] = (f16)v;
    } else if (gid < 16 * 768 + 16 * 640) {      // w2va[j][k]
      int g = gid - 16 * 768;
      int j = g / 640, k = g % 640;
      float v = (k < 256) ? va_w[j * 256 + k]
              : (k < 512) ? fsxva_w[j * 256 + (k - 256)]
                          : haxra_w[j * 128 + (k - 512)];
      ((f16*)((char*)ws + WS_W2VA))[j * 640 + k] = (f16)v;
    }
  }
}

// ---------------- main fused kernel ------------------------------------------
__global__ __launch_bounds__(TPB, 2)
void rengar_main(const int* __restrict__ pst_idx, const float* __restrict__ color_sign,
                 const float* __restrict__ sob_sign, const float* __restrict__ wtm,
                 const float* __restrict__ tempo_w, const float* __restrict__ fs_b,
                 const float* __restrict__ out_va_w, const float* __restrict__ out_fsxva_w,
                 const f16* __restrict__ ws, float* __restrict__ out) {
  __shared__ __align__(16) char smem[SMEM_SZ];

  const int tid  = threadIdx.x;
  const int lane = tid & 63;
  const int w    = tid >> 6;          // wave 0..7
  const int l15  = lane & 15;
  const int q    = lane >> 4;

  const f16* tabT = (const f16*)((const char*)ws + WS_TABT);

  // ---- hoist layer-1 A fragments: 6 tiles/wave, reused across all groups ----
  uint4 afr1[36];
  int   tbs[6];
  #pragma unroll
  for (int i = 0; i < 6; ++i) {
    int t  = w * 6 + i;
    int u0 = t * 16;
    tbs[i] = (u0 < 256) ? 0 : (u0 < 512) ? 1 : (u0 < 640) ? 2 : 3;
    const f16* ap = tabT + (u0 + l15) * K + q * 8;
    #pragma unroll
    for (int ks = 0; ks < 6; ++ks) afr1[i * 6 + ks] = *(const uint4*)(ap + ks * 32);
  }

  // ---- hoist layer-2 A fragments (split-K: fs -> waves 0-3, va -> waves 4-7)
  uint4 a2[6];
  if (w < 4) {
    const f16* A = (const f16*)((const char*)ws + WS_W2FS) + l15 * 768 + w * 192 + q * 8;
    #pragma unroll
    for (int ks = 0; ks < 6; ++ks) a2[ks] = *(const uint4*)(A + ks * 32);
  } else {
    const f16* A = (const f16*)((const char*)ws + WS_W2VA) + l15 * 640 + (w - 4) * 160 + q * 8;
    #pragma unroll
    for (int ks = 0; ks < 5; ++ks) a2[ks] = *(const uint4*)(A + ks * 32);
  }

  float bj = 0.f, w1j = 0.f, w2j = 0.f;
  if (tid < 256) {
    int j = tid >> 4;
    bj  = fs_b[j];
    w1j = out_va_w[j];
    w2j = out_fsxva_w[j];
  }

  // ---- prefetch group-0 inputs ----
  const int ebase = blockIdx.x * GPB * 512;
  int   vidx = pst_idx[ebase + tid];
  float cc   = color_sign[ebase + tid];
  float ss   = sob_sign[ebase + tid];
  float wtr  = wtm[blockIdx.x * GPB * MROWS + l15];

  #pragma unroll 1
  for (int g = 0; g < GPB; ++g) {
    const int r0 = (blockIdx.x * GPB + g) * MROWS;

    // ---- P1: zero count grid
    {
      int4 z = make_int4(0, 0, 0, 0);
      int4* p = (int4*)smem;
      #pragma unroll
      for (int i = 0; i < 6; ++i) p[tid + 512 * i] = z;
    }
    __syncthreads();

    // ---- P2: scatter (LDS int atomics, scale 2^16)
    {
      int* cntfx = (int*)smem;
      int  row = tid >> 5;
      int* base = cntfx + row * K + vidx;
      atomicAdd(base + 0 * MROWS * K, 65536);
      atomicAdd(base + 1 * MROWS * K, __float2int_rn(cc * 65536.f));
      atomicAdd(base + 2 * MROWS * K, __float2int_rn(ss * 65536.f));
      atomicAdd(base + 3 * MROWS * K, __float2int_rn(cc * ss * 65536.f));
    }
    // prefetch next group's inputs (latency hidden behind this group's work)
    float nwt = wtr;
    if (g + 1 < GPB) {
      int nb = ebase + (g + 1) * 512;
      vidx = pst_idx[nb + tid];
      cc   = color_sign[nb + tid];
      ss   = sob_sign[nb + tid];
      nwt  = wtm[r0 + MROWS + l15];
    }
    __syncthreads();

    // ---- P3: convert int -> f16 counts, re-layout [tb][row][200-u32-stride-100]
    {
      int vals[24];
      const int4* src = (const int4*)smem;
      #pragma unroll
      for (int i = 0; i < 6; ++i) {
        int4 t4 = src[tid * 6 + i];
        vals[4 * i + 0] = t4.x; vals[4 * i + 1] = t4.y;
        vals[4 * i + 2] = t4.z; vals[4 * i + 3] = t4.w;
      }
      __syncthreads();
      int lin = 24 * tid;
      int tb  = lin / 3072;
      int row = (lin / 192) & 15;
      int k0  = lin % 192;
      uint32_t* dst = (uint32_t*)smem + tb * 1600 + row * 100 + (k0 >> 1);
      const float inv = 1.f / 65536.f;
      #pragma unroll
      for (int i = 0; i < 12; ++i) {
        __half2 h = __floats2half2_rn(vals[2 * i] * inv, vals[2 * i + 1] * inv);
        union { __half2 h; uint32_t u; } cv; cv.h = h;
        dst[i] = cv.u;
      }
    }
    __syncthreads();

    // ---- P4: layer-1 GEMM (A register-resident, B from LDS counts)
    f32x4 acc[6];
    {
      uint4 bfr[6];
      int tb_cur = -1;
      #pragma unroll
      for (int i = 0; i < 6; ++i) {
        int tb = tbs[i];
        if (tb != tb_cur) {
          tb_cur = tb;
          #pragma unroll
          for (int ks = 0; ks < 6; ++ks) {
            const uint32_t* p = (const uint32_t*)smem + tb * 1600 + l15 * 100 + ks * 16 + q * 4;
            bfr[ks] = *(const uint4*)p;
          }
        }
        f32x4 a = {0.f, 0.f, 0.f, 0.f};
        #pragma unroll
        for (int ks = 0; ks < 6; ++ks)
          a = __builtin_amdgcn_mfma_f32_16x16x32_f16(bc8(afr1[i * 6 + ks]), bc8(bfr[ks]), a, 0, 0, 0);
        acc[i] = a;
      }
    }
    __syncthreads();   // counts dead; LDS becomes feature space

    // ---- P5: primary features (D: col=l15=batch row, m=q*4+reg=u)
    {
      #pragma unroll
      for (int i = 0; i < 6; ++i) {
        int t  = w * 6 + i;
        int u0 = t * 16;
        int tb = tbs[i];
        int m0 = u0 + q * 4;
        f32x4 a = acc[i];
        if (tb == 0) {
          __half2* d = (__half2*)(smem + l15 * (FS_STRIDE * 2) + m0 * 2);
          d[0] = __floats2half2_rn(clampv(a[0]), clampv(a[1]));
          d[1] = __floats2half2_rn(clampv(a[2]), clampv(a[3]));
        } else if (tb == 1) {
          int s0 = m0 - 256;
          float4 tw = *(const float4*)(tempo_w + s0);
          float b0 = clampv(a[0] + wtr * tw.x);
          float b1 = clampv(a[1] + wtr * tw.y);
          float b2 = clampv(a[2] + wtr * tw.z);
          float b3 = clampv(a[3] + wtr * tw.w);
          __half2* dv = (__half2*)(smem + VA_BASE + l15 * (VA_STRIDE * 2) + s0 * 2);
          dv[0] = __floats2half2_rn(b0, b1);
          dv[1] = __floats2half2_rn(b2, b3);
          __half2* df = (__half2*)(smem + l15 * (FS_STRIDE * 2) + (256 + s0) * 2);
          df[0] = __floats2half2_rn(fabsf(b0), fabsf(b1));
          df[1] = __floats2half2_rn(fabsf(b2), fabsf(b3));
        } else if (tb == 2) {
          int s0 = m0 - 512;
          __half2* d = (__half2*)(smem + l15 * (FS_STRIDE * 2) + (512 + s0) * 2);
          d[0] = __floats2half2_rn(clampv(a[0]), clampv(a[1]));
          d[1] = __floats2half2_rn(clampv(a[2]), clampv(a[3]));
        } else {
          int s0 = m0 - 640;
          __half2* d = (__half2*)(smem + l15 * (FS_STRIDE * 2) + (640 + s0) * 2);
          d[0] = __floats2half2_rn(clampv(a[0]), clampv(a[1]));
          d[1] = __floats2half2_rn(clampv(a[2]), clampv(a[3]));
        }
      }
    }
    __syncthreads();

    // ---- P6: derived features: ab, |h|, |r|, h*r
    {
      uint32_t* fs32 = (uint32_t*)smem;
      uint32_t* va32 = (uint32_t*)(smem + VA_BASE);
      #pragma unroll
      for (int it = 0; it < 6; ++it) {
        int p = tid + 512 * it;
        if (p < 2048) {
          int row = p >> 7, kp = p & 127;
          union { uint32_t u; __half2 h; } a, b, r;
          a.u = fs32[row * 388 + kp];
          b.u = va32[row * 324 + kp];
          r.h = __hmul2(a.h, b.h);
          va32[row * 324 + 128 + kp] = r.u;
        } else {
          int pc = p - 2048;
          int row = pc >> 6, kp = pc & 63;
          union { uint32_t u; __half2 h; } h2, r2, pr;
          h2.u = fs32[row * 388 + 256 + kp];
          r2.u = fs32[row * 388 + 320 + kp];
          pr.h = __hmul2(h2.h, r2.h);
          fs32[row * 388 + 256 + kp] = h2.u & 0x7FFF7FFFu;
          fs32[row * 388 + 320 + kp] = r2.u & 0x7FFF7FFFu;
          va32[row * 324 + 256 + kp] = pr.u;
        }
      }
    }
    __syncthreads();

    // ---- P7: layer-2 split-K across all 8 waves
    float* exch = (float*)(smem + EX_BASE);
    {
      f32x4 a2acc = {0.f, 0.f, 0.f, 0.f};
      if (w < 4) {
        #pragma unroll
        for (int ks = 0; ks < 6; ++ks) {
          int k = w * 192 + ks * 32 + q * 8;
          uint4 bf = *(const uint4*)(smem + l15 * (FS_STRIDE * 2) + k * 2);
          a2acc = __builtin_amdgcn_mfma_f32_16x16x32_f16(bc8(a2[ks]), bc8(bf), a2acc, 0, 0, 0);
        }
      } else {
        #pragma unroll
        for (int ks = 0; ks < 5; ++ks) {
          int k = (w - 4) * 160 + ks * 32 + q * 8;
          uint4 bf = *(const uint4*)(smem + VA_BASE + l15 * (VA_STRIDE * 2) + k * 2);
          a2acc = __builtin_amdgcn_mfma_f32_16x16x32_f16(bc8(a2[ks]), bc8(bf), a2acc, 0, 0, 0);
        }
      }
      #pragma unroll
      for (int r = 0; r < 4; ++r)
        exch[w * 256 + (q * 4 + r) * 16 + l15] = a2acc[r];
    }
    __syncthreads();

    // ---- P8: combine partials, output
    float* prod = (float*)(smem + PROD_BASE);
    if (tid < 256) {
      float f = exch[tid] + exch[256 + tid] + exch[512 + tid] + exch[768 + tid] + bj;
      f = clampv(f);
      float v = exch[1024 + tid] + exch[1280 + tid] + exch[1536 + tid] + exch[1792 + tid];
      v = clampv(v);
      prod[tid] = v * w1j + f * v * w2j;
    }
    __syncthreads();
    if (tid < 16) {
      float s = 0.f;
      #pragma unroll
      for (int j = 0; j < 16; ++j) s += prod[j * 16 + tid];
      out[r0 + tid] = s;
    }
    wtr = nwt;
  }
}

extern "C" void kernel_launch(void* const* d_in, const int* in_sizes, int n_in,
                              void* d_out, int out_size, void* d_ws, size_t ws_size,
                              hipStream_t stream) {
  const int*   pst_idx     = (const int*)  d_in[0];
  const float* color_sign  = (const float*)d_in[1];
  const float* sob_sign    = (const float*)d_in[2];
  const float* wtm         = (const float*)d_in[3];
  const float* emb_fs      = (const float*)d_in[4];
  const float* emb_va      = (const float*)d_in[5];
  const float* emb_ha      = (const float*)d_in[6];
  const float* emb_ra      = (const float*)d_in[7];
  const float* tempo_w     = (const float*)d_in[8];
  const float* fs_b        = (const float*)d_in[10];
  const float* fs_w        = (const float*)d_in[9];
  const float* absva_w     = (const float*)d_in[11];
  const float* absha_w     = (const float*)d_in[12];
  const float* absra_w     = (const float*)d_in[13];
  const float* va_w        = (const float*)d_in[14];
  const float* fsxva_w     = (const float*)d_in[15];
  const float* haxra_w     = (const float*)d_in[16];
  const float* out_va_w    = (const float*)d_in[17];
  const float* out_fsxva_w = (const float*)d_in[18];
  float* out = (float*)d_out;
  f16* ws = (f16*)d_ws;

  prepack<<<24 + 88, 256, 0, stream>>>(emb_fs, emb_va, emb_ha, emb_ra,
                                       fs_w, absva_w, absha_w, absra_w,
                                       va_w, fsxva_w, haxra_w, ws);
  rengar_main<<<NBLK, TPB, 0, stream>>>(pst_idx, color_sign, sob_sign, wtm,
                                        tempo_w, fs_b, out_va_w, out_fsxva_w,
                                        ws, out);
}